// Round 1
// baseline (2826.856 us; speedup 1.0000x reference)
//
#include <hip/hip_runtime.h>

// Problem dims
#define BB 16
#define SS 96
#define KK 10
#define FF 256
#define IH 64
#define IW 64
#define OCH 32
#define PH 31
#define PW 31
#define NPOS 961          // 31*31
#define FDIM 30752        // 32*961
#define NIMG 1536         // 16*96
#define KCH 3844          // 30752/8 split-K chunk

// Solver hyper-params
#define TAUI 20.0f        // 1/TAU
#define RHOC 10.0f
#define LRC  0.5f
#define NSTEPS 60

// ---------------- K1: conv3x3 valid + bias + relu + maxpool2x2 ----------------
// one thread per (img, pooled position), loops all 32 output channels.
// relu(max(conv)) == max(relu(conv)) (monotone), bias added before relu.
__global__ __launch_bounds__(256)
void conv_pool(const float* __restrict__ X, const float* __restrict__ W,
               const float* __restrict__ bias, float* __restrict__ pooled) {
    const int img = blockIdx.y;
    const int pos = blockIdx.x * 256 + threadIdx.x;
    if (pos >= NPOS) return;
    const int oy = pos / PW, ox = pos % PW;
    const int iy = 2 * oy, ix = 2 * ox;
    const float* xb = X + (size_t)img * 3 * IH * IW;
    float in[3][4][4];
#pragma unroll
    for (int c = 0; c < 3; c++)
#pragma unroll
        for (int r = 0; r < 4; r++) {
            const float* row = xb + ((size_t)c * IH + iy + r) * IW + ix;
            float2 p0 = *(const float2*)(row);
            float2 p1 = *(const float2*)(row + 2);
            in[c][r][0] = p0.x; in[c][r][1] = p0.y;
            in[c][r][2] = p1.x; in[c][r][3] = p1.y;
        }
    float* outp = pooled + (size_t)img * FDIM + pos;
    for (int oc = 0; oc < OCH; oc++) {
        float a00 = 0.f, a01 = 0.f, a10 = 0.f, a11 = 0.f;
#pragma unroll
        for (int c = 0; c < 3; c++)
#pragma unroll
            for (int ky = 0; ky < 3; ky++)
#pragma unroll
                for (int kx = 0; kx < 3; kx++) {
                    const float w = W[((oc * 3 + c) * 3 + ky) * 3 + kx];
                    a00 += in[c][ky + 0][kx + 0] * w;
                    a01 += in[c][ky + 0][kx + 1] * w;
                    a10 += in[c][ky + 1][kx + 0] * w;
                    a11 += in[c][ky + 1][kx + 1] * w;
                }
        float m = fmaxf(fmaxf(a00, a01), fmaxf(a10, a11)) + bias[oc];
        outp[(size_t)oc * NPOS] = fmaxf(m, 0.f);
    }
}

// ---------------- K2: FC GEMM fp32, 64x64 tile, BK=16, split-K=8, atomic accum ----------------
__global__ __launch_bounds__(256)
void fc_gemm(const float* __restrict__ Ap, const float* __restrict__ Wf,
             float* __restrict__ accout) {
    __shared__ float At[16][68];
    __shared__ float Wt[16][68];
    const int m0 = blockIdx.x * 64;
    const int n0 = blockIdx.y * 64;
    const int k0 = blockIdx.z * KCH;
    const int kend = k0 + KCH;
    const int tid = threadIdx.x;
    const int lm = tid >> 2;          // 0..63
    const int lk = (tid & 3) * 4;     // 0,4,8,12
    const int tm = tid >> 4, tn = tid & 15;
    float acc[4][4] = {{0.f}};
    for (int kb = k0; kb < kend; kb += 16) {
        const int gk = kb + lk;
        float4 av = make_float4(0.f, 0.f, 0.f, 0.f);
        float4 wv = make_float4(0.f, 0.f, 0.f, 0.f);
        if (gk + 4 <= kend) {  // KCH % 4 == 0, so remainder handled exactly
            av = *(const float4*)(Ap + (size_t)(m0 + lm) * FDIM + gk);
            wv = *(const float4*)(Wf + (size_t)(n0 + lm) * FDIM + gk);
        }
        __syncthreads();
        At[lk + 0][lm] = av.x; At[lk + 1][lm] = av.y;
        At[lk + 2][lm] = av.z; At[lk + 3][lm] = av.w;
        Wt[lk + 0][lm] = wv.x; Wt[lk + 1][lm] = wv.y;
        Wt[lk + 2][lm] = wv.z; Wt[lk + 3][lm] = wv.w;
        __syncthreads();
#pragma unroll
        for (int kk = 0; kk < 16; kk++) {
            float4 a4 = *(const float4*)&At[kk][tm * 4];
            float4 b4 = *(const float4*)&Wt[kk][tn * 4];
            float a[4] = {a4.x, a4.y, a4.z, a4.w};
            float b[4] = {b4.x, b4.y, b4.z, b4.w};
#pragma unroll
            for (int i = 0; i < 4; i++)
#pragma unroll
                for (int j = 0; j < 4; j++) acc[i][j] += a[i] * b[j];
        }
    }
#pragma unroll
    for (int i = 0; i < 4; i++)
#pragma unroll
        for (int j = 0; j < 4; j++)
            atomicAdd(&accout[(size_t)(m0 + tm * 4 + i) * FF + n0 + tn * 4 + j], acc[i][j]);
}

__global__ __launch_bounds__(256)
void bias_relu(float* __restrict__ f, const float* __restrict__ bias) {
    const int idx = blockIdx.x * 256 + threadIdx.x;
    f[idx] = fmaxf(f[idx] + bias[idx & 255], 0.f);
}

// ---------------- K3a: row squared norms ----------------
__global__ __launch_bounds__(512)
void rownorm(const float* __restrict__ feats, float* __restrict__ n2) {
    const int b = blockIdx.x;
    const int tid = threadIdx.x, hw = tid >> 5, l = tid & 31;
#pragma unroll
    for (int r = 0; r < 6; r++) {
        const int row = hw * 6 + r;
        const float* fr = feats + ((size_t)b * SS + row) * FF;
        float s = 0.f;
#pragma unroll
        for (int u = 0; u < 8; u++) { float v = fr[l + 32 * u]; s += v * v; }
#pragma unroll
        for (int mm = 16; mm >= 1; mm >>= 1) s += __shfl_xor(s, mm);
        if (l == 0) n2[b * SS + row] = s;
    }
}

// ---------------- K3b: D = clamp(n2_i + n2_j - 2<f_i,f_j>, 0) ----------------
__global__ __launch_bounds__(256)
void dmat(const float* __restrict__ feats, const float* __restrict__ n2,
          float* __restrict__ Dm) {
    const int i0 = blockIdx.x * 16, j0 = blockIdx.y * 16, b = blockIdx.z;
    __shared__ float fi[16][260], fj[16][260];
    const int tid = threadIdx.x;
    const int r = tid >> 4, c0 = (tid & 15) * 16;
    const float* fbase = feats + (size_t)b * SS * FF;
#pragma unroll
    for (int v = 0; v < 16; v += 4) {
        float4 a = *(const float4*)(fbase + (size_t)(i0 + r) * FF + c0 + v);
        float4 w = *(const float4*)(fbase + (size_t)(j0 + r) * FF + c0 + v);
        *(float4*)&fi[r][c0 + v] = a;
        *(float4*)&fj[r][c0 + v] = w;
    }
    __syncthreads();
    const int ti = tid >> 4, tj = tid & 15;
    float dot = 0.f;
#pragma unroll 4
    for (int f = 0; f < FF; f += 4) {
        float4 a = *(const float4*)&fi[ti][f];
        float4 w = *(const float4*)&fj[tj][f];
        dot += a.x * w.x + a.y * w.y + a.z * w.z + a.w * w.w;
    }
    const int i = i0 + ti, j = j0 + tj;
    const float d = n2[b * SS + i] + n2[b * SS + j] - 2.f * dot;
    Dm[((size_t)b * SS + i) * SS + j] = fmaxf(d, 0.f);
}

// ---------------- K4: robust-OT mirror/GD solve ----------------
// One block per (b,k). A[96][96] and D[96][96] resident in LDS.
// Coupling across k (smooth-max M) handled via published p + per-b 10-block
// device-scope barrier, double-buffered so one barrier per step suffices.
__global__ __launch_bounds__(512, 1)
void ot_kernel(const float* __restrict__ Dg, const float* __restrict__ Qg,
               const float* __restrict__ thetag, float* __restrict__ ppub,
               unsigned* __restrict__ bar, float* __restrict__ out) {
    const int bk = blockIdx.x;
    const int b = bk / KK, k = bk % KK;
    const int tid = threadIdx.x;
    const int hw = tid >> 5, l = tid & 31;

    __shared__ float Ash[SS * SS];      // 36 KB
    __shared__ float Dsh[SS * SS];      // 36 KB
    __shared__ float ppart[16 * SS];    // 6 KB
    __shared__ float cpart[16];
    __shared__ float Qsh[SS];
    __shared__ float marr[SS], zarr[SS];
    __shared__ float Msh[SS];
    __shared__ float pown[SS];
    __shared__ float costsh, lamsh;

    const float* Db = Dg + (size_t)b * SS * SS;
    for (int idx = tid; idx < SS * SS; idx += 512) {
        Dsh[idx] = Db[idx];
        Ash[idx] = 0.f;
    }
    if (tid < SS) Qsh[tid] = Qg[((size_t)b * KK + k) * SS + tid];
    const float th = thetag[k];
    unsigned* ctr = bar + b * 64;   // 256B-strided counters
    __syncthreads();

    unsigned target = 0;

    auto ppass = [&]() {
        for (int idx = tid; idx < 16 * SS; idx += 512) ppart[idx] = 0.f;
        if (tid < 16) cpart[tid] = 0.f;
        __syncthreads();
#pragma unroll
        for (int r = 0; r < 6; r++) {
            const int i = hw * 6 + r;
            const float a0 = Ash[i * SS + l], a1 = Ash[i * SS + l + 32], a2 = Ash[i * SS + l + 64];
            float m = fmaxf(a0, fmaxf(a1, a2));
#pragma unroll
            for (int mm = 16; mm >= 1; mm >>= 1) m = fmaxf(m, __shfl_xor(m, mm));
            const float e0 = expf(a0 - m), e1 = expf(a1 - m), e2 = expf(a2 - m);
            float z = e0 + e1 + e2;
            float cd = e0 * Dsh[i * SS + l] + e1 * Dsh[i * SS + l + 32] + e2 * Dsh[i * SS + l + 64];
#pragma unroll
            for (int mm = 16; mm >= 1; mm >>= 1) {
                z += __shfl_xor(z, mm);
                cd += __shfl_xor(cd, mm);
            }
            if (l == 0) { marr[i] = m; zarr[i] = z; }
            const float scale = Qsh[i] / z;
            ppart[hw * SS + l]      += scale * e0;
            ppart[hw * SS + l + 32] += scale * e1;
            ppart[hw * SS + l + 64] += scale * e2;
            if (l == 0) cpart[hw] += scale * cd;
        }
        __syncthreads();
        if (tid < SS) {
            float s = 0.f;
#pragma unroll
            for (int h = 0; h < 16; h++) s += ppart[h * SS + tid];
            pown[tid] = s;
        }
        if (tid == 0) {
            float c = 0.f;
#pragma unroll
            for (int h = 0; h < 16; h++) c += cpart[h];
            costsh = c;
        }
        __syncthreads();
    };

    auto publish_and_wait = [&](int buf) {
        if (tid < SS) ppub[(((size_t)buf * BB + b) * KK + k) * SS + tid] = pown[tid];
        __threadfence();          // release p stores to agent scope
        __syncthreads();
        target += KK;
        if (tid == 0) {
            __hip_atomic_fetch_add(ctr, 1u, __ATOMIC_RELEASE, __HIP_MEMORY_SCOPE_AGENT);
            while (__hip_atomic_load(ctr, __ATOMIC_ACQUIRE, __HIP_MEMORY_SCOPE_AGENT) < target)
                __builtin_amdgcn_s_sleep(4);
        }
        __syncthreads();
        // per-thread acquire so subsequent plain loads of peers' p are fresh
        (void)__hip_atomic_load(ctr, __ATOMIC_ACQUIRE, __HIP_MEMORY_SCOPE_AGENT);
    };

    ppass();                 // p_0, cost_0 from A=0
    publish_and_wait(0);

    for (int t = 0; t < NSTEPS; t++) {
        const int rbuf = t & 1;
        // M (smooth-max gradient) + lambda
        if (tid < SS) {
            const float* ps = ppub + (((size_t)rbuf * BB + b) * KK) * SS + tid;
            float v[KK];
            float mx = -1e30f;
#pragma unroll
            for (int kk2 = 0; kk2 < KK; kk2++) {
                v[kk2] = ps[kk2 * SS] * TAUI;
                mx = fmaxf(mx, v[kk2]);
            }
            float sum = 0.f;
#pragma unroll
            for (int kk2 = 0; kk2 < KK; kk2++) sum += expf(v[kk2] - mx);
            Msh[tid] = expf(v[k] - mx) / sum;
        }
        if (tid == 0) lamsh = 2.f * RHOC * fmaxf(costsh - th, 0.f);
        __syncthreads();
        const float lam = lamsh;
        // gradient pass: A -= LR * Q_i * s_ij * (g_ij - <s,g>)
#pragma unroll
        for (int r = 0; r < 6; r++) {
            const int i = hw * 6 + r;
            const float m = marr[i];
            const float rz = 1.0f / zarr[i];
            const float a0 = Ash[i * SS + l], a1 = Ash[i * SS + l + 32], a2 = Ash[i * SS + l + 64];
            const float s0 = expf(a0 - m) * rz, s1 = expf(a1 - m) * rz, s2 = expf(a2 - m) * rz;
            const float g0 = Msh[l]      + lam * Dsh[i * SS + l];
            const float g1 = Msh[l + 32] + lam * Dsh[i * SS + l + 32];
            const float g2 = Msh[l + 64] + lam * Dsh[i * SS + l + 64];
            float dt = s0 * g0 + s1 * g1 + s2 * g2;
#pragma unroll
            for (int mm = 16; mm >= 1; mm >>= 1) dt += __shfl_xor(dt, mm);
            const float cq = LRC * Qsh[i];
            Ash[i * SS + l]      = a0 - cq * (s0 * (g0 - dt));
            Ash[i * SS + l + 32] = a1 - cq * (s1 * (g1 - dt));
            Ash[i * SS + l + 64] = a2 - cq * (s2 * (g2 - dt));
        }
        __syncthreads();
        ppass();             // p_{t+1}, cost_{t+1}
        if (t < NSTEPS - 1) publish_and_wait((t + 1) & 1);
    }
    if (tid < SS) out[((size_t)b * KK + k) * SS + tid] = pown[tid];
}

// ---------------- launch ----------------
extern "C" void kernel_launch(void* const* d_in, const int* in_sizes, int n_in,
                              void* d_out, int out_size, void* d_ws, size_t ws_size,
                              hipStream_t stream) {
    const float* X     = (const float*)d_in[0];
    const float* Q     = (const float*)d_in[1];
    const float* convw = (const float*)d_in[2];
    const float* convb = (const float*)d_in[3];
    const float* fcw   = (const float*)d_in[4];
    const float* fcb   = (const float*)d_in[5];
    const float* theta = (const float*)d_in[6];
    float* out = (float*)d_out;

    char* ws = (char*)d_ws;
    size_t off = 0;
    auto take = [&](size_t nbytes) {
        char* p = ws + off;
        off += (nbytes + 255) & ~(size_t)255;
        return (void*)p;
    };
    float*    pooled = (float*)take((size_t)NIMG * FDIM * 4);   // ~189 MB
    float*    feats  = (float*)take((size_t)NIMG * FF * 4);     // 1.6 MB
    float*    n2     = (float*)take((size_t)NIMG * 4);
    float*    Dm     = (float*)take((size_t)BB * SS * SS * 4);
    float*    ppub   = (float*)take((size_t)2 * BB * KK * SS * 4);
    unsigned* bar    = (unsigned*)take((size_t)BB * 64 * 4);
    // total ws need ~192 MB

    hipMemsetAsync(feats, 0, (size_t)NIMG * FF * 4, stream);    // split-K atomic target
    hipMemsetAsync(bar, 0, (size_t)BB * 64 * 4, stream);        // barrier counters

    hipLaunchKernelGGL(conv_pool, dim3(4, NIMG), dim3(256), 0, stream, X, convw, convb, pooled);
    hipLaunchKernelGGL(fc_gemm, dim3(24, 4, 8), dim3(256), 0, stream, pooled, fcw, feats);
    hipLaunchKernelGGL(bias_relu, dim3(NIMG), dim3(256), 0, stream, feats, fcb);
    hipLaunchKernelGGL(rownorm, dim3(BB), dim3(512), 0, stream, feats, n2);
    hipLaunchKernelGGL(dmat, dim3(6, 6, BB), dim3(256), 0, stream, feats, n2, Dm);
    hipLaunchKernelGGL(ot_kernel, dim3(BB * KK), dim3(512), 0, stream, Dm, Q, theta, ppub, bar, out);
}

// Round 2
// 1093.460 us; speedup vs baseline: 2.5852x; 2.5852x over previous
//
#include <hip/hip_runtime.h>

// Problem dims
#define BB 16
#define SS 96
#define KK 10
#define FF 256
#define IH 64
#define IW 64
#define OCH 32
#define PH 31
#define PW 31
#define NPOS 961          // 31*31
#define FDIM 30752        // 32*961
#define NIMG 1536         // 16*96
#define KCH 3844          // 30752/8 split-K chunk

// Solver hyper-params
#define TAUI 20.0f        // 1/TAU
#define RHOC 10.0f
#define LRC  0.5f
#define NSTEPS 60

// ---------------- K1: conv3x3 valid + bias + relu + maxpool2x2 ----------------
__global__ __launch_bounds__(256)
void conv_pool(const float* __restrict__ X, const float* __restrict__ W,
               const float* __restrict__ bias, float* __restrict__ pooled) {
    const int img = blockIdx.y;
    const int pos = blockIdx.x * 256 + threadIdx.x;
    if (pos >= NPOS) return;
    const int oy = pos / PW, ox = pos % PW;
    const int iy = 2 * oy, ix = 2 * ox;
    const float* xb = X + (size_t)img * 3 * IH * IW;
    float in[3][4][4];
#pragma unroll
    for (int c = 0; c < 3; c++)
#pragma unroll
        for (int r = 0; r < 4; r++) {
            const float* row = xb + ((size_t)c * IH + iy + r) * IW + ix;
            float2 p0 = *(const float2*)(row);
            float2 p1 = *(const float2*)(row + 2);
            in[c][r][0] = p0.x; in[c][r][1] = p0.y;
            in[c][r][2] = p1.x; in[c][r][3] = p1.y;
        }
    float* outp = pooled + (size_t)img * FDIM + pos;
    for (int oc = 0; oc < OCH; oc++) {
        float a00 = 0.f, a01 = 0.f, a10 = 0.f, a11 = 0.f;
#pragma unroll
        for (int c = 0; c < 3; c++)
#pragma unroll
            for (int ky = 0; ky < 3; ky++)
#pragma unroll
                for (int kx = 0; kx < 3; kx++) {
                    const float w = W[((oc * 3 + c) * 3 + ky) * 3 + kx];
                    a00 += in[c][ky + 0][kx + 0] * w;
                    a01 += in[c][ky + 0][kx + 1] * w;
                    a10 += in[c][ky + 1][kx + 0] * w;
                    a11 += in[c][ky + 1][kx + 1] * w;
                }
        float m = fmaxf(fmaxf(a00, a01), fmaxf(a10, a11)) + bias[oc];
        outp[(size_t)oc * NPOS] = fmaxf(m, 0.f);
    }
}

// ---------------- K2: FC GEMM fp32, 64x64 tile, BK=16, split-K=8, atomic accum ----------------
__global__ __launch_bounds__(256)
void fc_gemm(const float* __restrict__ Ap, const float* __restrict__ Wf,
             float* __restrict__ accout) {
    __shared__ float At[16][68];
    __shared__ float Wt[16][68];
    const int m0 = blockIdx.x * 64;
    const int n0 = blockIdx.y * 64;
    const int k0 = blockIdx.z * KCH;
    const int kend = k0 + KCH;
    const int tid = threadIdx.x;
    const int lm = tid >> 2;          // 0..63
    const int lk = (tid & 3) * 4;     // 0,4,8,12
    const int tm = tid >> 4, tn = tid & 15;
    float acc[4][4] = {{0.f}};
    for (int kb = k0; kb < kend; kb += 16) {
        const int gk = kb + lk;
        float4 av = make_float4(0.f, 0.f, 0.f, 0.f);
        float4 wv = make_float4(0.f, 0.f, 0.f, 0.f);
        if (gk + 4 <= kend) {
            av = *(const float4*)(Ap + (size_t)(m0 + lm) * FDIM + gk);
            wv = *(const float4*)(Wf + (size_t)(n0 + lm) * FDIM + gk);
        }
        __syncthreads();
        At[lk + 0][lm] = av.x; At[lk + 1][lm] = av.y;
        At[lk + 2][lm] = av.z; At[lk + 3][lm] = av.w;
        Wt[lk + 0][lm] = wv.x; Wt[lk + 1][lm] = wv.y;
        Wt[lk + 2][lm] = wv.z; Wt[lk + 3][lm] = wv.w;
        __syncthreads();
#pragma unroll
        for (int kk = 0; kk < 16; kk++) {
            float4 a4 = *(const float4*)&At[kk][tm * 4];
            float4 b4 = *(const float4*)&Wt[kk][tn * 4];
            float a[4] = {a4.x, a4.y, a4.z, a4.w};
            float b[4] = {b4.x, b4.y, b4.z, b4.w};
#pragma unroll
            for (int i = 0; i < 4; i++)
#pragma unroll
                for (int j = 0; j < 4; j++) acc[i][j] += a[i] * b[j];
        }
    }
#pragma unroll
    for (int i = 0; i < 4; i++)
#pragma unroll
        for (int j = 0; j < 4; j++)
            atomicAdd(&accout[(size_t)(m0 + tm * 4 + i) * FF + n0 + tn * 4 + j], acc[i][j]);
}

__global__ __launch_bounds__(256)
void bias_relu(float* __restrict__ f, const float* __restrict__ bias) {
    const int idx = blockIdx.x * 256 + threadIdx.x;
    f[idx] = fmaxf(f[idx] + bias[idx & 255], 0.f);
}

// ---------------- K3a: row squared norms ----------------
__global__ __launch_bounds__(512)
void rownorm(const float* __restrict__ feats, float* __restrict__ n2) {
    const int b = blockIdx.x;
    const int tid = threadIdx.x, hw = tid >> 5, l = tid & 31;
#pragma unroll
    for (int r = 0; r < 6; r++) {
        const int row = hw * 6 + r;
        const float* fr = feats + ((size_t)b * SS + row) * FF;
        float s = 0.f;
#pragma unroll
        for (int u = 0; u < 8; u++) { float v = fr[l + 32 * u]; s += v * v; }
#pragma unroll
        for (int mm = 16; mm >= 1; mm >>= 1) s += __shfl_xor(s, mm);
        if (l == 0) n2[b * SS + row] = s;
    }
}

// ---------------- K3b: D = clamp(n2_i + n2_j - 2<f_i,f_j>, 0) ----------------
__global__ __launch_bounds__(256)
void dmat(const float* __restrict__ feats, const float* __restrict__ n2,
          float* __restrict__ Dm) {
    const int i0 = blockIdx.x * 16, j0 = blockIdx.y * 16, b = blockIdx.z;
    __shared__ float fi[16][260], fj[16][260];
    const int tid = threadIdx.x;
    const int r = tid >> 4, c0 = (tid & 15) * 16;
    const float* fbase = feats + (size_t)b * SS * FF;
#pragma unroll
    for (int v = 0; v < 16; v += 4) {
        float4 a = *(const float4*)(fbase + (size_t)(i0 + r) * FF + c0 + v);
        float4 w = *(const float4*)(fbase + (size_t)(j0 + r) * FF + c0 + v);
        *(float4*)&fi[r][c0 + v] = a;
        *(float4*)&fj[r][c0 + v] = w;
    }
    __syncthreads();
    const int ti = tid >> 4, tj = tid & 15;
    float dot = 0.f;
#pragma unroll 4
    for (int f = 0; f < FF; f += 4) {
        float4 a = *(const float4*)&fi[ti][f];
        float4 w = *(const float4*)&fj[tj][f];
        dot += a.x * w.x + a.y * w.y + a.z * w.z + a.w * w.w;
    }
    const int i = i0 + ti, j = j0 + tj;
    const float d = n2[b * SS + i] + n2[b * SS + j] - 2.f * dot;
    Dm[((size_t)b * SS + i) * SS + j] = fmaxf(d, 0.f);
}

// ---------------- K4: robust-OT solve, v2 ----------------
// One block per (b,k). A, e=exp(A-m), D-rows, 1/z all register-resident
// (half-wave owns 6 rows; lane owns 3 columns/row). Grad-update and next
// softmax/p/cost pass fused into one row loop. Cross-k coupling (M, via p)
// exchanged with RELAXED agent-scope atomics (bypass L1/L2 -> coherence
// point; no acquire/release cache wb/inv storms), ordered by one explicit
// s_waitcnt vmcnt(0) before the per-b counter bump.
__global__ __launch_bounds__(512)
void ot_kernel(const float* __restrict__ Dg, const float* __restrict__ Qg,
               const float* __restrict__ thetag, float* __restrict__ ppub,
               unsigned* __restrict__ bar, float* __restrict__ out) {
    const int bk = blockIdx.x;
    const int b = bk / KK, k = bk % KK;
    const int tid = threadIdx.x;
    const int hw = tid >> 5, l = tid & 31;

    __shared__ float ppart[16][SS];   // 6 KB
    __shared__ float cpart[16];
    __shared__ float Msh[SS];
    __shared__ float pown[SS];
    __shared__ float costsh, lamsh;

    float a[6][3], e[6][3], dre[6][3], rz[6], qi[6];

    const float* Db = Dg + (size_t)b * SS * SS;
    const float* Qb = Qg + ((size_t)b * KK + k) * SS;
#pragma unroll
    for (int r = 0; r < 6; r++) {
        const int i = hw * 6 + r;
#pragma unroll
        for (int u = 0; u < 3; u++) dre[r][u] = Db[i * SS + l + 32 * u];
        qi[r] = Qb[i];
    }
    const float th = thetag[k];
    unsigned* ctr = bar + b * 64;   // 256B-strided counters
    unsigned target = 0;

    auto publish_and_wait = [&](int buf) {
        if (tid < SS)
            __hip_atomic_store(&ppub[(((size_t)buf * BB + b) * KK + k) * SS + tid],
                               pown[tid], __ATOMIC_RELAXED, __HIP_MEMORY_SCOPE_AGENT);
        asm volatile("s_waitcnt vmcnt(0)" ::: "memory");
        __syncthreads();
        target += KK;
        if (tid == 0) {
            __hip_atomic_fetch_add(ctr, 1u, __ATOMIC_RELAXED, __HIP_MEMORY_SCOPE_AGENT);
            while (__hip_atomic_load(ctr, __ATOMIC_RELAXED, __HIP_MEMORY_SCOPE_AGENT) < target)
                __builtin_amdgcn_s_sleep(2);
        }
        __syncthreads();
    };

    // ---- init pass: A=0 -> e=1, z=96, uniform softmax ----
    {
        float pp0 = 0.f, pp1 = 0.f, pp2 = 0.f, cc = 0.f;
#pragma unroll
        for (int r = 0; r < 6; r++) {
#pragma unroll
            for (int u = 0; u < 3; u++) { a[r][u] = 0.f; e[r][u] = 1.f; }
            rz[r] = 1.f / 96.f;
            float cd = dre[r][0] + dre[r][1] + dre[r][2];
#pragma unroll
            for (int mm = 16; mm >= 1; mm >>= 1) cd += __shfl_xor(cd, mm);
            const float scale = qi[r] * rz[r];
            pp0 += scale; pp1 += scale; pp2 += scale;
            cc += scale * cd;
        }
        ppart[hw][l] = pp0; ppart[hw][l + 32] = pp1; ppart[hw][l + 64] = pp2;
        if (l == 0) cpart[hw] = cc;
        __syncthreads();
        if (tid < SS) {
            float s = 0.f;
#pragma unroll
            for (int h = 0; h < 16; h++) s += ppart[h][tid];
            pown[tid] = s;
        }
        if (tid == 0) {
            float c = 0.f;
#pragma unroll
            for (int h = 0; h < 16; h++) c += cpart[h];
            costsh = c;
        }
        __syncthreads();
    }
    publish_and_wait(0);

    for (int t = 0; t < NSTEPS; t++) {
        const int rbuf = t & 1;
        // M (smooth-max gradient across k) + lambda
        if (tid < SS) {
            const float* ps = ppub + (((size_t)rbuf * BB + b) * KK) * SS + tid;
            float v[KK];
            float mx = -1e30f;
#pragma unroll
            for (int kk2 = 0; kk2 < KK; kk2++) {
                v[kk2] = __hip_atomic_load(&ps[kk2 * SS], __ATOMIC_RELAXED,
                                           __HIP_MEMORY_SCOPE_AGENT) * TAUI;
                mx = fmaxf(mx, v[kk2]);
            }
            float sum = 0.f;
#pragma unroll
            for (int kk2 = 0; kk2 < KK; kk2++) sum += expf(v[kk2] - mx);
            Msh[tid] = expf(v[k] - mx) / sum;
        }
        if (tid == 0) lamsh = 2.f * RHOC * fmaxf(costsh - th, 0.f);
        __syncthreads();
        const float lam = lamsh;

        float pp0 = 0.f, pp1 = 0.f, pp2 = 0.f, cc = 0.f;
#pragma unroll
        for (int r = 0; r < 6; r++) {
            // gradient at A_t using cached e, rz (s = e * rz)
            const float g0 = Msh[l]      + lam * dre[r][0];
            const float g1 = Msh[l + 32] + lam * dre[r][1];
            const float g2 = Msh[l + 64] + lam * dre[r][2];
            const float s0 = e[r][0] * rz[r], s1 = e[r][1] * rz[r], s2 = e[r][2] * rz[r];
            float dt = s0 * g0 + s1 * g1 + s2 * g2;
#pragma unroll
            for (int mm = 16; mm >= 1; mm >>= 1) dt += __shfl_xor(dt, mm);
            const float cq = LRC * qi[r];
            a[r][0] -= cq * (s0 * (g0 - dt));
            a[r][1] -= cq * (s1 * (g1 - dt));
            a[r][2] -= cq * (s2 * (g2 - dt));
            // fused next pass: softmax stats, p-partials, cost at A_{t+1}
            float m = fmaxf(a[r][0], fmaxf(a[r][1], a[r][2]));
#pragma unroll
            for (int mm = 16; mm >= 1; mm >>= 1) m = fmaxf(m, __shfl_xor(m, mm));
            const float e0 = expf(a[r][0] - m), e1 = expf(a[r][1] - m), e2 = expf(a[r][2] - m);
            float z = e0 + e1 + e2;
            float cd = e0 * dre[r][0] + e1 * dre[r][1] + e2 * dre[r][2];
#pragma unroll
            for (int mm = 16; mm >= 1; mm >>= 1) {
                z += __shfl_xor(z, mm);
                cd += __shfl_xor(cd, mm);
            }
            const float rzz = 1.f / z;
            e[r][0] = e0; e[r][1] = e1; e[r][2] = e2; rz[r] = rzz;
            const float scale = qi[r] * rzz;
            pp0 += scale * e0; pp1 += scale * e1; pp2 += scale * e2;
            cc += scale * cd;
        }
        ppart[hw][l] = pp0; ppart[hw][l + 32] = pp1; ppart[hw][l + 64] = pp2;
        if (l == 0) cpart[hw] = cc;
        __syncthreads();
        if (tid < SS) {
            float s = 0.f;
#pragma unroll
            for (int h = 0; h < 16; h++) s += ppart[h][tid];
            pown[tid] = s;
        }
        if (tid == 0) {
            float c = 0.f;
#pragma unroll
            for (int h = 0; h < 16; h++) c += cpart[h];
            costsh = c;
        }
        __syncthreads();
        if (t < NSTEPS - 1) publish_and_wait((t + 1) & 1);
    }
    if (tid < SS) out[((size_t)b * KK + k) * SS + tid] = pown[tid];
}

// ---------------- launch ----------------
extern "C" void kernel_launch(void* const* d_in, const int* in_sizes, int n_in,
                              void* d_out, int out_size, void* d_ws, size_t ws_size,
                              hipStream_t stream) {
    const float* X     = (const float*)d_in[0];
    const float* Q     = (const float*)d_in[1];
    const float* convw = (const float*)d_in[2];
    const float* convb = (const float*)d_in[3];
    const float* fcw   = (const float*)d_in[4];
    const float* fcb   = (const float*)d_in[5];
    const float* theta = (const float*)d_in[6];
    float* out = (float*)d_out;

    char* ws = (char*)d_ws;
    size_t off = 0;
    auto take = [&](size_t nbytes) {
        char* p = ws + off;
        off += (nbytes + 255) & ~(size_t)255;
        return (void*)p;
    };
    float*    pooled = (float*)take((size_t)NIMG * FDIM * 4);   // ~189 MB
    float*    feats  = (float*)take((size_t)NIMG * FF * 4);     // 1.6 MB
    float*    n2     = (float*)take((size_t)NIMG * 4);
    float*    Dm     = (float*)take((size_t)BB * SS * SS * 4);
    float*    ppub   = (float*)take((size_t)2 * BB * KK * SS * 4);
    unsigned* bar    = (unsigned*)take((size_t)BB * 64 * 4);

    hipMemsetAsync(feats, 0, (size_t)NIMG * FF * 4, stream);    // split-K atomic target
    hipMemsetAsync(bar, 0, (size_t)BB * 64 * 4, stream);        // barrier counters

    hipLaunchKernelGGL(conv_pool, dim3(4, NIMG), dim3(256), 0, stream, X, convw, convb, pooled);
    hipLaunchKernelGGL(fc_gemm, dim3(24, 4, 8), dim3(256), 0, stream, pooled, fcw, feats);
    hipLaunchKernelGGL(bias_relu, dim3(NIMG), dim3(256), 0, stream, feats, fcb);
    hipLaunchKernelGGL(rownorm, dim3(BB), dim3(512), 0, stream, feats, n2);
    hipLaunchKernelGGL(dmat, dim3(6, 6, BB), dim3(256), 0, stream, feats, n2, Dm);
    hipLaunchKernelGGL(ot_kernel, dim3(BB * KK), dim3(512), 0, stream, Dm, Q, theta, ppub, bar, out);
}

// Round 3
// 769.549 us; speedup vs baseline: 3.6734x; 1.4209x over previous
//
#include <hip/hip_runtime.h>

// Problem dims
#define BB 16
#define SS 96
#define KK 10
#define FF 256
#define IH 64
#define IW 64
#define OCH 32
#define PH 31
#define PW 31
#define NPOS 961          // 31*31
#define FDIM 30752        // 32*961
#define NIMG 1536         // 16*96

// Solver hyper-params
#define TAUI 20.0f        // 1/TAU
#define RHOC 10.0f
#define LRC  0.5f
#define NSTEPS 60

// fc_gemm split-K
#define KSPLIT 16
#define KCHE 1952         // 61 K-steps of 32; last chunk 1472 (46 steps)

typedef _Float16 v8hf __attribute__((ext_vector_type(8)));
typedef _Float16 v4hf __attribute__((ext_vector_type(4)));
typedef float v4f __attribute__((ext_vector_type(4)));

// ---------------- K0: fc weight fp32 -> fp16 ----------------
__global__ __launch_bounds__(256)
void wcast(const float* __restrict__ w, _Float16* __restrict__ wh) {
    const size_t i = ((size_t)blockIdx.x * 256 + threadIdx.x) * 4;
    float4 v = *(const float4*)(w + i);
    v4hf o = {(_Float16)v.x, (_Float16)v.y, (_Float16)v.z, (_Float16)v.w};
    *(v4hf*)(wh + i) = o;
}

// ---------------- K1: conv3x3 valid + bias + relu + maxpool2x2 -> fp16 ----------------
__global__ __launch_bounds__(256)
void conv_pool(const float* __restrict__ X, const float* __restrict__ W,
               const float* __restrict__ bias, _Float16* __restrict__ pooled) {
    const int img = blockIdx.y;
    const int pos = blockIdx.x * 256 + threadIdx.x;
    if (pos >= NPOS) return;
    const int oy = pos / PW, ox = pos % PW;
    const int iy = 2 * oy, ix = 2 * ox;
    const float* xb = X + (size_t)img * 3 * IH * IW;
    float in[3][4][4];
#pragma unroll
    for (int c = 0; c < 3; c++)
#pragma unroll
        for (int r = 0; r < 4; r++) {
            const float* row = xb + ((size_t)c * IH + iy + r) * IW + ix;
            float2 p0 = *(const float2*)(row);
            float2 p1 = *(const float2*)(row + 2);
            in[c][r][0] = p0.x; in[c][r][1] = p0.y;
            in[c][r][2] = p1.x; in[c][r][3] = p1.y;
        }
    _Float16* outp = pooled + (size_t)img * FDIM + pos;
    for (int oc = 0; oc < OCH; oc++) {
        float a00 = 0.f, a01 = 0.f, a10 = 0.f, a11 = 0.f;
#pragma unroll
        for (int c = 0; c < 3; c++)
#pragma unroll
            for (int ky = 0; ky < 3; ky++)
#pragma unroll
                for (int kx = 0; kx < 3; kx++) {
                    const float w = W[((oc * 3 + c) * 3 + ky) * 3 + kx];
                    a00 += in[c][ky + 0][kx + 0] * w;
                    a01 += in[c][ky + 0][kx + 1] * w;
                    a10 += in[c][ky + 1][kx + 0] * w;
                    a11 += in[c][ky + 1][kx + 1] * w;
                }
        float m = fmaxf(fmaxf(a00, a01), fmaxf(a10, a11)) + bias[oc];
        outp[(size_t)oc * NPOS] = (_Float16)fmaxf(m, 0.f);
    }
}

// ---------------- K2: FC GEMM fp16 MFMA, 128x64 tile, split-K=16, atomic accum ----------------
// LDS row stride 56 halves (112B): 16B-aligned for b128, bank starts (28*m)%32
// cycle over 8 distinct bank-quads -> 2-way aliasing only (free, m136).
__global__ __launch_bounds__(256)
void fc_gemm(const _Float16* __restrict__ Ah, const _Float16* __restrict__ Wh,
             float* __restrict__ accout) {
    __shared__ _Float16 Asl[128 * 56];
    __shared__ _Float16 Bsl[64 * 56];
    const int m0 = blockIdx.x * 128, n0 = blockIdx.y * 64;
    const int k0 = blockIdx.z * KCHE;
    const int kend = min(k0 + KCHE, FDIM);
    const int ksteps = (kend - k0) >> 5;
    const int tid = threadIdx.x;
    const int wave = tid >> 6, lane = tid & 63;
    const int quad = lane >> 4, l16 = lane & 15;
    const int wm = (wave >> 1) * 64, wn = (wave & 1) * 32;
    // staging indices: A tile 128 rows x 32 halves (2 thr/row x 2 chunks),
    //                  B tile  64 rows x 32 halves (4 thr/row x 1 chunk)
    const int ar = tid >> 1, ac = (tid & 1) * 16;
    const int br = tid >> 2, bc = (tid & 3) * 8;
    const _Float16* Ag = Ah + (size_t)(m0 + ar) * FDIM + ac;
    const _Float16* Bg = Wh + (size_t)(n0 + br) * FDIM + bc;

    v4f acc[4][2];
#pragma unroll
    for (int i = 0; i < 4; i++)
#pragma unroll
        for (int j = 0; j < 2; j++) acc[i][j] = (v4f)(0.f);

    for (int s = 0; s < ksteps; s++) {
        const int gk = k0 + (s << 5);
        uint4 a0 = *(const uint4*)(Ag + gk);
        uint4 a1 = *(const uint4*)(Ag + gk + 8);
        uint4 b0 = *(const uint4*)(Bg + gk);
        __syncthreads();
        *(uint4*)&Asl[ar * 56 + ac] = a0;
        *(uint4*)&Asl[ar * 56 + ac + 8] = a1;
        *(uint4*)&Bsl[br * 56 + bc] = b0;
        __syncthreads();
        v8hf af[4], bf[2];
#pragma unroll
        for (int mt = 0; mt < 4; mt++)
            af[mt] = *(const v8hf*)&Asl[(wm + mt * 16 + l16) * 56 + quad * 8];
#pragma unroll
        for (int nt = 0; nt < 2; nt++)
            bf[nt] = *(const v8hf*)&Bsl[(wn + nt * 16 + l16) * 56 + quad * 8];
#pragma unroll
        for (int mt = 0; mt < 4; mt++)
#pragma unroll
            for (int nt = 0; nt < 2; nt++)
                acc[mt][nt] = __builtin_amdgcn_mfma_f32_16x16x32_f16(
                    af[mt], bf[nt], acc[mt][nt], 0, 0, 0);
    }
#pragma unroll
    for (int mt = 0; mt < 4; mt++)
#pragma unroll
        for (int nt = 0; nt < 2; nt++)
#pragma unroll
            for (int i = 0; i < 4; i++) {
                const int gm = m0 + wm + mt * 16 + quad * 4 + i;
                const int gn = n0 + wn + nt * 16 + l16;
                atomicAdd(&accout[(size_t)gm * FF + gn], acc[mt][nt][i]);
            }
}

__global__ __launch_bounds__(256)
void bias_relu(float* __restrict__ f, const float* __restrict__ bias) {
    const int idx = blockIdx.x * 256 + threadIdx.x;
    f[idx] = fmaxf(f[idx] + bias[idx & 255], 0.f);
}

// ---------------- K3a: row squared norms ----------------
__global__ __launch_bounds__(512)
void rownorm(const float* __restrict__ feats, float* __restrict__ n2) {
    const int b = blockIdx.x;
    const int tid = threadIdx.x, hw = tid >> 5, l = tid & 31;
#pragma unroll
    for (int r = 0; r < 6; r++) {
        const int row = hw * 6 + r;
        const float* fr = feats + ((size_t)b * SS + row) * FF;
        float s = 0.f;
#pragma unroll
        for (int u = 0; u < 8; u++) { float v = fr[l + 32 * u]; s += v * v; }
#pragma unroll
        for (int mm = 16; mm >= 1; mm >>= 1) s += __shfl_xor(s, mm);
        if (l == 0) n2[b * SS + row] = s;
    }
}

// ---------------- K3b: D = clamp(n2_i + n2_j - 2<f_i,f_j>, 0) ----------------
__global__ __launch_bounds__(256)
void dmat(const float* __restrict__ feats, const float* __restrict__ n2,
          float* __restrict__ Dm) {
    const int i0 = blockIdx.x * 16, j0 = blockIdx.y * 16, b = blockIdx.z;
    __shared__ float fi[16][260], fj[16][260];
    const int tid = threadIdx.x;
    const int r = tid >> 4, c0 = (tid & 15) * 16;
    const float* fbase = feats + (size_t)b * SS * FF;
#pragma unroll
    for (int v = 0; v < 16; v += 4) {
        float4 a = *(const float4*)(fbase + (size_t)(i0 + r) * FF + c0 + v);
        float4 w = *(const float4*)(fbase + (size_t)(j0 + r) * FF + c0 + v);
        *(float4*)&fi[r][c0 + v] = a;
        *(float4*)&fj[r][c0 + v] = w;
    }
    __syncthreads();
    const int ti = tid >> 4, tj = tid & 15;
    float dot = 0.f;
#pragma unroll 4
    for (int f = 0; f < FF; f += 4) {
        float4 a = *(const float4*)&fi[ti][f];
        float4 w = *(const float4*)&fj[tj][f];
        dot += a.x * w.x + a.y * w.y + a.z * w.z + a.w * w.w;
    }
    const int i = i0 + ti, j = j0 + tj;
    const float d = n2[b * SS + i] + n2[b * SS + j] - 2.f * dot;
    Dm[((size_t)b * SS + i) * SS + j] = fmaxf(d, 0.f);
}

// ---------------- K4: robust-OT solve (register-resident, relaxed-atomic barrier) ----------------
__global__ __launch_bounds__(512)
void ot_kernel(const float* __restrict__ Dg, const float* __restrict__ Qg,
               const float* __restrict__ thetag, float* __restrict__ ppub,
               unsigned* __restrict__ bar, float* __restrict__ out) {
    const int bk = blockIdx.x;
    const int b = bk / KK, k = bk % KK;
    const int tid = threadIdx.x;
    const int hw = tid >> 5, l = tid & 31;

    __shared__ float ppart[16][SS];
    __shared__ float cpart[16];
    __shared__ float Msh[SS];
    __shared__ float pown[SS];
    __shared__ float costsh, lamsh;

    float a[6][3], e[6][3], dre[6][3], rz[6], qi[6];

    const float* Db = Dg + (size_t)b * SS * SS;
    const float* Qb = Qg + ((size_t)b * KK + k) * SS;
#pragma unroll
    for (int r = 0; r < 6; r++) {
        const int i = hw * 6 + r;
#pragma unroll
        for (int u = 0; u < 3; u++) dre[r][u] = Db[i * SS + l + 32 * u];
        qi[r] = Qb[i];
    }
    const float th = thetag[k];
    unsigned* ctr = bar + b * 64;
    unsigned target = 0;

    auto publish_and_wait = [&](int buf) {
        if (tid < SS)
            __hip_atomic_store(&ppub[(((size_t)buf * BB + b) * KK + k) * SS + tid],
                               pown[tid], __ATOMIC_RELAXED, __HIP_MEMORY_SCOPE_AGENT);
        asm volatile("s_waitcnt vmcnt(0)" ::: "memory");
        __syncthreads();
        target += KK;
        if (tid == 0) {
            __hip_atomic_fetch_add(ctr, 1u, __ATOMIC_RELAXED, __HIP_MEMORY_SCOPE_AGENT);
            while (__hip_atomic_load(ctr, __ATOMIC_RELAXED, __HIP_MEMORY_SCOPE_AGENT) < target)
                __builtin_amdgcn_s_sleep(2);
        }
        __syncthreads();
    };

    {
        float pp0 = 0.f, pp1 = 0.f, pp2 = 0.f, cc = 0.f;
#pragma unroll
        for (int r = 0; r < 6; r++) {
#pragma unroll
            for (int u = 0; u < 3; u++) { a[r][u] = 0.f; e[r][u] = 1.f; }
            rz[r] = 1.f / 96.f;
            float cd = dre[r][0] + dre[r][1] + dre[r][2];
#pragma unroll
            for (int mm = 16; mm >= 1; mm >>= 1) cd += __shfl_xor(cd, mm);
            const float scale = qi[r] * rz[r];
            pp0 += scale; pp1 += scale; pp2 += scale;
            cc += scale * cd;
        }
        ppart[hw][l] = pp0; ppart[hw][l + 32] = pp1; ppart[hw][l + 64] = pp2;
        if (l == 0) cpart[hw] = cc;
        __syncthreads();
        if (tid < SS) {
            float s = 0.f;
#pragma unroll
            for (int h = 0; h < 16; h++) s += ppart[h][tid];
            pown[tid] = s;
        }
        if (tid == 0) {
            float c = 0.f;
#pragma unroll
            for (int h = 0; h < 16; h++) c += cpart[h];
            costsh = c;
        }
        __syncthreads();
    }
    publish_and_wait(0);

    for (int t = 0; t < NSTEPS; t++) {
        const int rbuf = t & 1;
        if (tid < SS) {
            const float* ps = ppub + (((size_t)rbuf * BB + b) * KK) * SS + tid;
            float v[KK];
            float mx = -1e30f;
#pragma unroll
            for (int kk2 = 0; kk2 < KK; kk2++) {
                v[kk2] = __hip_atomic_load(&ps[kk2 * SS], __ATOMIC_RELAXED,
                                           __HIP_MEMORY_SCOPE_AGENT) * TAUI;
                mx = fmaxf(mx, v[kk2]);
            }
            float sum = 0.f;
#pragma unroll
            for (int kk2 = 0; kk2 < KK; kk2++) sum += expf(v[kk2] - mx);
            Msh[tid] = expf(v[k] - mx) / sum;
        }
        if (tid == 0) lamsh = 2.f * RHOC * fmaxf(costsh - th, 0.f);
        __syncthreads();
        const float lam = lamsh;

        float pp0 = 0.f, pp1 = 0.f, pp2 = 0.f, cc = 0.f;
#pragma unroll
        for (int r = 0; r < 6; r++) {
            const float g0 = Msh[l]      + lam * dre[r][0];
            const float g1 = Msh[l + 32] + lam * dre[r][1];
            const float g2 = Msh[l + 64] + lam * dre[r][2];
            const float s0 = e[r][0] * rz[r], s1 = e[r][1] * rz[r], s2 = e[r][2] * rz[r];
            float dt = s0 * g0 + s1 * g1 + s2 * g2;
#pragma unroll
            for (int mm = 16; mm >= 1; mm >>= 1) dt += __shfl_xor(dt, mm);
            const float cq = LRC * qi[r];
            a[r][0] -= cq * (s0 * (g0 - dt));
            a[r][1] -= cq * (s1 * (g1 - dt));
            a[r][2] -= cq * (s2 * (g2 - dt));
            float m = fmaxf(a[r][0], fmaxf(a[r][1], a[r][2]));
#pragma unroll
            for (int mm = 16; mm >= 1; mm >>= 1) m = fmaxf(m, __shfl_xor(m, mm));
            const float e0 = expf(a[r][0] - m), e1 = expf(a[r][1] - m), e2 = expf(a[r][2] - m);
            float z = e0 + e1 + e2;
            float cd = e0 * dre[r][0] + e1 * dre[r][1] + e2 * dre[r][2];
#pragma unroll
            for (int mm = 16; mm >= 1; mm >>= 1) {
                z += __shfl_xor(z, mm);
                cd += __shfl_xor(cd, mm);
            }
            const float rzz = 1.f / z;
            e[r][0] = e0; e[r][1] = e1; e[r][2] = e2; rz[r] = rzz;
            const float scale = qi[r] * rzz;
            pp0 += scale * e0; pp1 += scale * e1; pp2 += scale * e2;
            cc += scale * cd;
        }
        ppart[hw][l] = pp0; ppart[hw][l + 32] = pp1; ppart[hw][l + 64] = pp2;
        if (l == 0) cpart[hw] = cc;
        __syncthreads();
        if (tid < SS) {
            float s = 0.f;
#pragma unroll
            for (int h = 0; h < 16; h++) s += ppart[h][tid];
            pown[tid] = s;
        }
        if (tid == 0) {
            float c = 0.f;
#pragma unroll
            for (int h = 0; h < 16; h++) c += cpart[h];
            costsh = c;
        }
        __syncthreads();
        if (t < NSTEPS - 1) publish_and_wait((t + 1) & 1);
    }
    if (tid < SS) out[((size_t)b * KK + k) * SS + tid] = pown[tid];
}

// ---------------- launch ----------------
extern "C" void kernel_launch(void* const* d_in, const int* in_sizes, int n_in,
                              void* d_out, int out_size, void* d_ws, size_t ws_size,
                              hipStream_t stream) {
    const float* X     = (const float*)d_in[0];
    const float* Q     = (const float*)d_in[1];
    const float* convw = (const float*)d_in[2];
    const float* convb = (const float*)d_in[3];
    const float* fcw   = (const float*)d_in[4];
    const float* fcb   = (const float*)d_in[5];
    const float* theta = (const float*)d_in[6];
    float* out = (float*)d_out;

    char* ws = (char*)d_ws;
    size_t off = 0;
    auto take = [&](size_t nbytes) {
        char* p = ws + off;
        off += (nbytes + 255) & ~(size_t)255;
        return (void*)p;
    };
    _Float16* pooled = (_Float16*)take((size_t)NIMG * FDIM * 2);  // 94.5 MB
    _Float16* Wh     = (_Float16*)take((size_t)FF * FDIM * 2);    // 15.7 MB
    float*    feats  = (float*)take((size_t)NIMG * FF * 4);
    float*    n2     = (float*)take((size_t)NIMG * 4);
    float*    Dm     = (float*)take((size_t)BB * SS * SS * 4);
    float*    ppub   = (float*)take((size_t)2 * BB * KK * SS * 4);
    unsigned* bar    = (unsigned*)take((size_t)BB * 64 * 4);

    hipMemsetAsync(feats, 0, (size_t)NIMG * FF * 4, stream);
    hipMemsetAsync(bar, 0, (size_t)BB * 64 * 4, stream);

    hipLaunchKernelGGL(wcast, dim3((FF * FDIM) / 1024), dim3(256), 0, stream, fcw, Wh);
    hipLaunchKernelGGL(conv_pool, dim3(4, NIMG), dim3(256), 0, stream, X, convw, convb, pooled);
    hipLaunchKernelGGL(fc_gemm, dim3(12, 4, KSPLIT), dim3(256), 0, stream, pooled, Wh, feats);
    hipLaunchKernelGGL(bias_relu, dim3(NIMG), dim3(256), 0, stream, feats, fcb);
    hipLaunchKernelGGL(rownorm, dim3(BB), dim3(512), 0, stream, feats, n2);
    hipLaunchKernelGGL(dmat, dim3(6, 6, BB), dim3(256), 0, stream, feats, n2, Dm);
    hipLaunchKernelGGL(ot_kernel, dim3(BB * KK), dim3(512), 0, stream, Dm, Q, theta, ppub, bar, out);
}

// Round 4
// 700.170 us; speedup vs baseline: 4.0374x; 1.0991x over previous
//
#include <hip/hip_runtime.h>

// Problem dims
#define BB 16
#define SS 96
#define KK 10
#define FF 256
#define IH 64
#define IW 64
#define OCH 32
#define PH 31
#define PW 31
#define NPOS 961          // 31*31
#define FDIM 30752        // 32*961
#define NIMG 1536         // 16*96

// Solver hyper-params
#define TAUI 20.0f        // 1/TAU
#define RHOC 10.0f
#define LRC  0.5f
#define NSTEPS 60

// fc_gemm split-K
#define KSPLIT 16
#define KCHE 1952

typedef _Float16 v8hf __attribute__((ext_vector_type(8)));
typedef _Float16 v4hf __attribute__((ext_vector_type(4)));
typedef float v4f __attribute__((ext_vector_type(4)));

// ---------------- K0: fc weight fp32 -> fp16 ----------------
__global__ __launch_bounds__(256)
void wcast(const float* __restrict__ w, _Float16* __restrict__ wh) {
    const size_t i = ((size_t)blockIdx.x * 256 + threadIdx.x) * 4;
    float4 v = *(const float4*)(w + i);
    v4hf o = {(_Float16)v.x, (_Float16)v.y, (_Float16)v.z, (_Float16)v.w};
    *(v4hf*)(wh + i) = o;
}

// ---------------- K1: conv3x3 valid + bias + relu + maxpool2x2 -> fp16 ----------------
__global__ __launch_bounds__(256)
void conv_pool(const float* __restrict__ X, const float* __restrict__ W,
               const float* __restrict__ bias, _Float16* __restrict__ pooled) {
    const int img = blockIdx.y;
    const int pos = blockIdx.x * 256 + threadIdx.x;
    if (pos >= NPOS) return;
    const int oy = pos / PW, ox = pos % PW;
    const int iy = 2 * oy, ix = 2 * ox;
    const float* xb = X + (size_t)img * 3 * IH * IW;
    float in[3][4][4];
#pragma unroll
    for (int c = 0; c < 3; c++)
#pragma unroll
        for (int r = 0; r < 4; r++) {
            const float* row = xb + ((size_t)c * IH + iy + r) * IW + ix;
            float2 p0 = *(const float2*)(row);
            float2 p1 = *(const float2*)(row + 2);
            in[c][r][0] = p0.x; in[c][r][1] = p0.y;
            in[c][r][2] = p1.x; in[c][r][3] = p1.y;
        }
    _Float16* outp = pooled + (size_t)img * FDIM + pos;
    for (int oc = 0; oc < OCH; oc++) {
        float a00 = 0.f, a01 = 0.f, a10 = 0.f, a11 = 0.f;
#pragma unroll
        for (int c = 0; c < 3; c++)
#pragma unroll
            for (int ky = 0; ky < 3; ky++)
#pragma unroll
                for (int kx = 0; kx < 3; kx++) {
                    const float w = W[((oc * 3 + c) * 3 + ky) * 3 + kx];
                    a00 += in[c][ky + 0][kx + 0] * w;
                    a01 += in[c][ky + 0][kx + 1] * w;
                    a10 += in[c][ky + 1][kx + 0] * w;
                    a11 += in[c][ky + 1][kx + 1] * w;
                }
        float m = fmaxf(fmaxf(a00, a01), fmaxf(a10, a11)) + bias[oc];
        outp[(size_t)oc * NPOS] = (_Float16)fmaxf(m, 0.f);
    }
}

// ---------------- K2: FC GEMM fp16 MFMA, 128x64 tile, split-K=16, atomic accum ----------------
__global__ __launch_bounds__(256)
void fc_gemm(const _Float16* __restrict__ Ah, const _Float16* __restrict__ Wh,
             float* __restrict__ accout) {
    __shared__ _Float16 Asl[128 * 56];
    __shared__ _Float16 Bsl[64 * 56];
    const int m0 = blockIdx.x * 128, n0 = blockIdx.y * 64;
    const int k0 = blockIdx.z * KCHE;
    const int kend = min(k0 + KCHE, FDIM);
    const int ksteps = (kend - k0) >> 5;
    const int tid = threadIdx.x;
    const int wave = tid >> 6, lane = tid & 63;
    const int quad = lane >> 4, l16 = lane & 15;
    const int wm = (wave >> 1) * 64, wn = (wave & 1) * 32;
    const int ar = tid >> 1, ac = (tid & 1) * 16;
    const int br = tid >> 2, bc = (tid & 3) * 8;
    const _Float16* Ag = Ah + (size_t)(m0 + ar) * FDIM + ac;
    const _Float16* Bg = Wh + (size_t)(n0 + br) * FDIM + bc;

    v4f acc[4][2];
#pragma unroll
    for (int i = 0; i < 4; i++)
#pragma unroll
        for (int j = 0; j < 2; j++) acc[i][j] = (v4f)(0.f);

    for (int s = 0; s < ksteps; s++) {
        const int gk = k0 + (s << 5);
        uint4 a0 = *(const uint4*)(Ag + gk);
        uint4 a1 = *(const uint4*)(Ag + gk + 8);
        uint4 b0 = *(const uint4*)(Bg + gk);
        __syncthreads();
        *(uint4*)&Asl[ar * 56 + ac] = a0;
        *(uint4*)&Asl[ar * 56 + ac + 8] = a1;
        *(uint4*)&Bsl[br * 56 + bc] = b0;
        __syncthreads();
        v8hf af[4], bf[2];
#pragma unroll
        for (int mt = 0; mt < 4; mt++)
            af[mt] = *(const v8hf*)&Asl[(wm + mt * 16 + l16) * 56 + quad * 8];
#pragma unroll
        for (int nt = 0; nt < 2; nt++)
            bf[nt] = *(const v8hf*)&Bsl[(wn + nt * 16 + l16) * 56 + quad * 8];
#pragma unroll
        for (int mt = 0; mt < 4; mt++)
#pragma unroll
            for (int nt = 0; nt < 2; nt++)
                acc[mt][nt] = __builtin_amdgcn_mfma_f32_16x16x32_f16(
                    af[mt], bf[nt], acc[mt][nt], 0, 0, 0);
    }
#pragma unroll
    for (int mt = 0; mt < 4; mt++)
#pragma unroll
        for (int nt = 0; nt < 2; nt++)
#pragma unroll
            for (int i = 0; i < 4; i++) {
                const int gm = m0 + wm + mt * 16 + quad * 4 + i;
                const int gn = n0 + wn + nt * 16 + l16;
                atomicAdd(&accout[(size_t)gm * FF + gn], acc[mt][nt][i]);
            }
}

__global__ __launch_bounds__(256)
void bias_relu(float* __restrict__ f, const float* __restrict__ bias) {
    const int idx = blockIdx.x * 256 + threadIdx.x;
    f[idx] = fmaxf(f[idx] + bias[idx & 255], 0.f);
}

// ---------------- K3a: row squared norms ----------------
__global__ __launch_bounds__(512)
void rownorm(const float* __restrict__ feats, float* __restrict__ n2) {
    const int b = blockIdx.x;
    const int tid = threadIdx.x, hw = tid >> 5, l = tid & 31;
#pragma unroll
    for (int r = 0; r < 6; r++) {
        const int row = hw * 6 + r;
        const float* fr = feats + ((size_t)b * SS + row) * FF;
        float s = 0.f;
#pragma unroll
        for (int u = 0; u < 8; u++) { float v = fr[l + 32 * u]; s += v * v; }
#pragma unroll
        for (int mm = 16; mm >= 1; mm >>= 1) s += __shfl_xor(s, mm);
        if (l == 0) n2[b * SS + row] = s;
    }
}

// ---------------- K3b: D = clamp(n2_i + n2_j - 2<f_i,f_j>, 0) ----------------
__global__ __launch_bounds__(256)
void dmat(const float* __restrict__ feats, const float* __restrict__ n2,
          float* __restrict__ Dm) {
    const int i0 = blockIdx.x * 16, j0 = blockIdx.y * 16, b = blockIdx.z;
    __shared__ float fi[16][260], fj[16][260];
    const int tid = threadIdx.x;
    const int r = tid >> 4, c0 = (tid & 15) * 16;
    const float* fbase = feats + (size_t)b * SS * FF;
#pragma unroll
    for (int v = 0; v < 16; v += 4) {
        float4 a = *(const float4*)(fbase + (size_t)(i0 + r) * FF + c0 + v);
        float4 w = *(const float4*)(fbase + (size_t)(j0 + r) * FF + c0 + v);
        *(float4*)&fi[r][c0 + v] = a;
        *(float4*)&fj[r][c0 + v] = w;
    }
    __syncthreads();
    const int ti = tid >> 4, tj = tid & 15;
    float dot = 0.f;
#pragma unroll 4
    for (int f = 0; f < FF; f += 4) {
        float4 a = *(const float4*)&fi[ti][f];
        float4 w = *(const float4*)&fj[tj][f];
        dot += a.x * w.x + a.y * w.y + a.z * w.z + a.w * w.w;
    }
    const int i = i0 + ti, j = j0 + tj;
    const float d = n2[b * SS + i] + n2[b * SS + j] - 2.f * dot;
    Dm[((size_t)b * SS + i) * SS + j] = fmaxf(d, 0.f);
}

// ---------------- K4: robust-OT solve, v3 (batched cross-row reductions for ILP) ----------------
// One block per (b,k); half-wave owns 6 rows, lane owns 3 cols/row. All 5-step
// shuffle ladders are interleaved across the 6 rows so the ds_swizzle latency
// (~30-40 cyc) is paid once per ladder step, not once per row per step.
__global__ __launch_bounds__(512)
void ot_kernel(const float* __restrict__ Dg, const float* __restrict__ Qg,
               const float* __restrict__ thetag, float* __restrict__ ppub,
               unsigned* __restrict__ bar, float* __restrict__ out) {
    const int bk = blockIdx.x;
    const int b = bk / KK, k = bk % KK;
    const int tid = threadIdx.x;
    const int hw = tid >> 5, l = tid & 31;

    __shared__ float ppart[16][SS];
    __shared__ float cpart[16];
    __shared__ float Msh[SS];
    __shared__ float pown[SS];
    __shared__ float costsh, lamsh;

    float a[6][3], e[6][3], dre[6][3], rz[6], qi[6];

    const float* Db = Dg + (size_t)b * SS * SS;
    const float* Qb = Qg + ((size_t)b * KK + k) * SS;
#pragma unroll
    for (int r = 0; r < 6; r++) {
        const int i = hw * 6 + r;
#pragma unroll
        for (int u = 0; u < 3; u++) dre[r][u] = Db[i * SS + l + 32 * u];
        qi[r] = Qb[i];
    }
    const float th = thetag[k];
    unsigned* ctr = bar + b * 64;
    unsigned target = 0;

    auto publish_and_wait = [&](int buf) {
        if (tid < SS)
            __hip_atomic_store(&ppub[(((size_t)buf * BB + b) * KK + k) * SS + tid],
                               pown[tid], __ATOMIC_RELAXED, __HIP_MEMORY_SCOPE_AGENT);
        asm volatile("s_waitcnt vmcnt(0)" ::: "memory");
        __syncthreads();
        target += KK;
        if (tid == 0) {
            __hip_atomic_fetch_add(ctr, 1u, __ATOMIC_RELAXED, __HIP_MEMORY_SCOPE_AGENT);
            while (__hip_atomic_load(ctr, __ATOMIC_RELAXED, __HIP_MEMORY_SCOPE_AGENT) < target)
                __builtin_amdgcn_s_sleep(2);
        }
        __syncthreads();
    };

    // reduce ppart columns -> pown, total cost -> costsh, lam for NEXT step
    auto collect = [&]() {
        __syncthreads();
        if (tid < SS) {
            float s = 0.f;
#pragma unroll
            for (int h = 0; h < 16; h++) s += ppart[h][tid];
            pown[tid] = s;
        }
        if (tid == 0) {
            float c = 0.f;
#pragma unroll
            for (int h = 0; h < 16; h++) c += cpart[h];
            costsh = c;
            lamsh = 2.f * RHOC * fmaxf(c - th, 0.f);
        }
        __syncthreads();
    };

    // ---- init pass: A=0 -> e=1, z=96 ----
    {
        float cd[6];
#pragma unroll
        for (int r = 0; r < 6; r++) {
#pragma unroll
            for (int u = 0; u < 3; u++) { a[r][u] = 0.f; e[r][u] = 1.f; }
            rz[r] = 1.f / 96.f;
            cd[r] = dre[r][0] + dre[r][1] + dre[r][2];
        }
#pragma unroll
        for (int mm = 16; mm >= 1; mm >>= 1)
#pragma unroll
            for (int r = 0; r < 6; r++) cd[r] += __shfl_xor(cd[r], mm);
        float pp0 = 0.f, cc = 0.f;
#pragma unroll
        for (int r = 0; r < 6; r++) {
            const float scale = qi[r] * rz[r];
            pp0 += scale;
            cc += scale * cd[r];
        }
        ppart[hw][l] = pp0; ppart[hw][l + 32] = pp0; ppart[hw][l + 64] = pp0;
        if (l == 0) cpart[hw] = cc;
        collect();
    }
    publish_and_wait(0);

    for (int t = 0; t < NSTEPS; t++) {
        const int rbuf = t & 1;
        // M (smooth-max gradient across k)
        if (tid < SS) {
            const float* ps = ppub + (((size_t)rbuf * BB + b) * KK) * SS + tid;
            float v[KK];
            float mx = -1e30f;
#pragma unroll
            for (int kk2 = 0; kk2 < KK; kk2++) {
                v[kk2] = __hip_atomic_load(&ps[kk2 * SS], __ATOMIC_RELAXED,
                                           __HIP_MEMORY_SCOPE_AGENT) * TAUI;
                mx = fmaxf(mx, v[kk2]);
            }
            float sum = 0.f;
#pragma unroll
            for (int kk2 = 0; kk2 < KK; kk2++) sum += __expf(v[kk2] - mx);
            Msh[tid] = __expf(v[k] - mx) * __builtin_amdgcn_rcpf(sum);
        }
        __syncthreads();
        const float lam = lamsh;
        const float M0 = Msh[l], M1 = Msh[l + 32], M2 = Msh[l + 64];

        // phase 1: gradient dot partials, batch-reduce
        float g[6][3], dt[6];
#pragma unroll
        for (int r = 0; r < 6; r++) {
            g[r][0] = fmaf(lam, dre[r][0], M0);
            g[r][1] = fmaf(lam, dre[r][1], M1);
            g[r][2] = fmaf(lam, dre[r][2], M2);
            dt[r] = (e[r][0] * g[r][0] + e[r][1] * g[r][1] + e[r][2] * g[r][2]) * rz[r];
        }
#pragma unroll
        for (int mm = 16; mm >= 1; mm >>= 1)
#pragma unroll
            for (int r = 0; r < 6; r++) dt[r] += __shfl_xor(dt[r], mm);

        // phase 2: update A, row maxima, batch-reduce (max)
        float mrow[6];
#pragma unroll
        for (int r = 0; r < 6; r++) {
            const float cq = LRC * qi[r] * rz[r];
            a[r][0] -= cq * e[r][0] * (g[r][0] - dt[r]);
            a[r][1] -= cq * e[r][1] * (g[r][1] - dt[r]);
            a[r][2] -= cq * e[r][2] * (g[r][2] - dt[r]);
            mrow[r] = fmaxf(a[r][0], fmaxf(a[r][1], a[r][2]));
        }
#pragma unroll
        for (int mm = 16; mm >= 1; mm >>= 1)
#pragma unroll
            for (int r = 0; r < 6; r++) mrow[r] = fmaxf(mrow[r], __shfl_xor(mrow[r], mm));

        // phase 3: exp, z & cost partials, batch-reduce (12 interleaved chains)
        float zz[6], cd[6];
#pragma unroll
        for (int r = 0; r < 6; r++) {
            e[r][0] = __expf(a[r][0] - mrow[r]);
            e[r][1] = __expf(a[r][1] - mrow[r]);
            e[r][2] = __expf(a[r][2] - mrow[r]);
            zz[r] = e[r][0] + e[r][1] + e[r][2];
            cd[r] = e[r][0] * dre[r][0] + e[r][1] * dre[r][1] + e[r][2] * dre[r][2];
        }
#pragma unroll
        for (int mm = 16; mm >= 1; mm >>= 1)
#pragma unroll
            for (int r = 0; r < 6; r++) {
                zz[r] += __shfl_xor(zz[r], mm);
                cd[r] += __shfl_xor(cd[r], mm);
            }

        // phase 4: p-partials + cost
        float pp0 = 0.f, pp1 = 0.f, pp2 = 0.f, cc = 0.f;
#pragma unroll
        for (int r = 0; r < 6; r++) {
            const float rzz = __builtin_amdgcn_rcpf(zz[r]);
            rz[r] = rzz;
            const float scale = qi[r] * rzz;
            pp0 += scale * e[r][0];
            pp1 += scale * e[r][1];
            pp2 += scale * e[r][2];
            cc += scale * cd[r];
        }
        ppart[hw][l] = pp0; ppart[hw][l + 32] = pp1; ppart[hw][l + 64] = pp2;
        if (l == 0) cpart[hw] = cc;
        collect();
        if (t < NSTEPS - 1) publish_and_wait((t + 1) & 1);
    }
    if (tid < SS) out[((size_t)b * KK + k) * SS + tid] = pown[tid];
}

// ---------------- launch ----------------
extern "C" void kernel_launch(void* const* d_in, const int* in_sizes, int n_in,
                              void* d_out, int out_size, void* d_ws, size_t ws_size,
                              hipStream_t stream) {
    const float* X     = (const float*)d_in[0];
    const float* Q     = (const float*)d_in[1];
    const float* convw = (const float*)d_in[2];
    const float* convb = (const float*)d_in[3];
    const float* fcw   = (const float*)d_in[4];
    const float* fcb   = (const float*)d_in[5];
    const float* theta = (const float*)d_in[6];
    float* out = (float*)d_out;

    char* ws = (char*)d_ws;
    size_t off = 0;
    auto take = [&](size_t nbytes) {
        char* p = ws + off;
        off += (nbytes + 255) & ~(size_t)255;
        return (void*)p;
    };
    _Float16* pooled = (_Float16*)take((size_t)NIMG * FDIM * 2);
    _Float16* Wh     = (_Float16*)take((size_t)FF * FDIM * 2);
    float*    feats  = (float*)take((size_t)NIMG * FF * 4);
    float*    n2     = (float*)take((size_t)NIMG * 4);
    float*    Dm     = (float*)take((size_t)BB * SS * SS * 4);
    float*    ppub   = (float*)take((size_t)2 * BB * KK * SS * 4);
    unsigned* bar    = (unsigned*)take((size_t)BB * 64 * 4);

    hipMemsetAsync(feats, 0, (size_t)NIMG * FF * 4, stream);
    hipMemsetAsync(bar, 0, (size_t)BB * 64 * 4, stream);

    hipLaunchKernelGGL(wcast, dim3((FF * FDIM) / 1024), dim3(256), 0, stream, fcw, Wh);
    hipLaunchKernelGGL(conv_pool, dim3(4, NIMG), dim3(256), 0, stream, X, convw, convb, pooled);
    hipLaunchKernelGGL(fc_gemm, dim3(12, 4, KSPLIT), dim3(256), 0, stream, pooled, Wh, feats);
    hipLaunchKernelGGL(bias_relu, dim3(NIMG), dim3(256), 0, stream, feats, fcb);
    hipLaunchKernelGGL(rownorm, dim3(BB), dim3(512), 0, stream, feats, n2);
    hipLaunchKernelGGL(dmat, dim3(6, 6, BB), dim3(256), 0, stream, feats, n2, Dm);
    hipLaunchKernelGGL(ot_kernel, dim3(BB * KK), dim3(512), 0, stream, Dm, Q, theta, ppub, bar, out);
}